// Round 11
// baseline (404.116 us; speedup 1.0000x reference)
//
#include <hip/hip_runtime.h>
#include <math.h>

// ---------------------------------------------------------------------------
// SimpleGNN (4-layer GCN + mean pool + sigmoid) on MI355X.
//   - CSR build: atomic-free bucket sort (R6).
//   - norm factored into GEMM epilogue; aggregation = pure gather-sum
//   - h kept in BF16; layers 2,3 = bf16 MFMA GEMM (16x16x32) -> FP8 gather
//     buffer. agg (R10/11): 8 lanes/row x dwordx4 = 8 edges per gather instr,
//     32 edges/iter in flight; NT colarr reads protect gbuf's L2 residency.
//     NOTE: __builtin_nontemporal_* needs scalar/clang-vector ptrs, not HIP
//     int4 structs (R10 compile fail) -> i32x4 ext vector for NT stores.
//   - layer1 reassociated (aggregate 6-dim x first); layer4 projected to
//     scalar first; pool via sorted-batch segment bounds + wave reduce
// ---------------------------------------------------------------------------

typedef float f32x2 __attribute__((ext_vector_type(2)));
typedef float f32x4 __attribute__((ext_vector_type(4)));
typedef int   i32x4 __attribute__((ext_vector_type(4)));
typedef short bf16x8 __attribute__((ext_vector_type(8)));   // 8 bf16 = 4 VGPRs

#define BKT    64     // nodes per bucket (shift 6)
#define NCH    128    // edge chunks
#define MAXBUK 2048   // LDS bucket counters (nbuk = 1563 @ n=100k)
#define DCAP   2048   // per-bucket LDS colarr staging
#define WTP    136    // padded row length of transposed W (bf16)

// ---- CSR pass A: per-chunk LDS histogram over buckets ----
__global__ __launch_bounds__(256) void hist_bucket(const int* __restrict__ dst,
                                                   int* __restrict__ hmatT,
                                                   int e, int nbuk) {
    __shared__ int h[MAXBUK];
    for (int i = threadIdx.x; i < nbuk; i += 256) h[i] = 0;
    __syncthreads();
    const int per = (e + NCH - 1) / NCH;
    const int beg = blockIdx.x * per;
    const int end = min(beg + per, e);
    for (int i = beg + threadIdx.x; i < end; i += 256)
        atomicAdd(&h[dst[i] >> 6], 1);          // LDS atomic
    __syncthreads();
    for (int b = threadIdx.x; b < nbuk; b += 256)
        hmatT[b * NCH + blockIdx.x] = h[b];
}

// ---- CSR pass B1: per-bucket exclusive scan over its NCH chunk-counts ----
__global__ __launch_bounds__(256) void scan_chunks(int* __restrict__ hmatT,
                                                   int* __restrict__ totals, int nbuk) {
    int b = blockIdx.x * 4 + (threadIdx.x >> 6);
    if (b >= nbuk) return;
    const int lane = threadIdx.x & 63;
    int* row = hmatT + b * NCH;
    int v0 = row[lane], v1 = row[64 + lane];
    int x = v0;
    #pragma unroll
    for (int off = 1; off < 64; off <<= 1) { int y = __shfl_up(x, off); if (lane >= off) x += y; }
    int carry = __shfl(x, 63);
    int e0 = x - v0;
    int x1 = v1;
    #pragma unroll
    for (int off = 1; off < 64; off <<= 1) { int y = __shfl_up(x1, off); if (lane >= off) x1 += y; }
    int e1 = x1 - v1 + carry;
    int tot = __shfl(x1, 63) + carry;
    row[lane] = e0;
    row[64 + lane] = e1;
    if (lane == 0) totals[b] = tot;
}

// ---- CSR pass B2: single-block chunked exclusive scan ----
__global__ void scan_kernel(const int* __restrict__ counts, int* __restrict__ rowptr, int n) {
    __shared__ int wsum[16];
    __shared__ int carry_s;
    const int tid  = threadIdx.x;            // 1024 threads
    const int lane = tid & 63, wid = tid >> 6;
    if (tid == 0) carry_s = 0;
    __syncthreads();
    const int nchunk = (n + 4095) >> 12;
    for (int c = 0; c < nchunk; ++c) {
        int i0 = (c << 12) + tid * 4;
        int4 v = make_int4(0, 0, 0, 0);
        if (i0 + 3 < n) {
            v = *(const int4*)(counts + i0);
        } else {
            if (i0     < n) v.x = counts[i0];
            if (i0 + 1 < n) v.y = counts[i0 + 1];
            if (i0 + 2 < n) v.z = counts[i0 + 2];
            if (i0 + 3 < n) v.w = counts[i0 + 3];
        }
        int s1 = v.x, s2 = s1 + v.y, s3 = s2 + v.z, s4 = s3 + v.w;
        int x = s4;
        #pragma unroll
        for (int off = 1; off < 64; off <<= 1) {
            int y = __shfl_up(x, off);
            if (lane >= off) x += y;
        }
        if (lane == 63) wsum[wid] = x;
        __syncthreads();
        if (wid == 0) {
            int s = (lane < 16) ? wsum[lane] : 0;
            #pragma unroll
            for (int off = 1; off < 16; off <<= 1) {
                int y = __shfl_up(s, off);
                if (lane >= off) s += y;
            }
            if (lane < 16) wsum[lane] = s;
        }
        __syncthreads();
        int carry = carry_s + ((wid > 0) ? wsum[wid - 1] : 0);
        int excl  = carry + x - s4;
        if (i0     < n) rowptr[i0 + 1] = excl + s1;
        if (i0 + 1 < n) rowptr[i0 + 2] = excl + s2;
        if (i0 + 2 < n) rowptr[i0 + 3] = excl + s3;
        if (i0 + 3 < n) rowptr[i0 + 4] = excl + s4;
        __syncthreads();
        if (tid == 1023) carry_s = carry + x;
        __syncthreads();
    }
    if (tid == 0) rowptr[0] = 0;
}

// ---- CSR pass C: partition edges into bucket-grouped order ----
__global__ __launch_bounds__(256) void partition_kernel(const int* __restrict__ src,
                                                        const int* __restrict__ dst,
                                                        const int* __restrict__ hmatT,
                                                        const int* __restrict__ bukBase,
                                                        int* __restrict__ part,
                                                        int e, int nbuk) {
    __shared__ int cur[MAXBUK];
    for (int b = threadIdx.x; b < nbuk; b += 256)
        cur[b] = bukBase[b] + hmatT[b * NCH + blockIdx.x];
    __syncthreads();
    const int per = (e + NCH - 1) / NCH;
    const int beg = blockIdx.x * per;
    const int end = min(beg + per, e);
    for (int i = beg + threadIdx.x; i < end; i += 256) {
        int d = dst[i], s = src[i];
        int pos = atomicAdd(&cur[d >> 6], 1);   // LDS atomic
        part[pos] = (d & 63) | (s << 6);        // s < 2^17 -> fits
    }
}

// ---- CSR pass D: per-bucket local CSR finish + fused dinv ----
__global__ __launch_bounds__(256) void bucket_csr(const int* __restrict__ part,
                                                  const int* __restrict__ bukBase,
                                                  int* __restrict__ colarr,
                                                  int* __restrict__ rowptr,
                                                  float* __restrict__ dinv,
                                                  int n, int e) {
    __shared__ int hist[BKT];
    __shared__ int cursor[BKT];
    __shared__ int loc[DCAP];
    const int b = blockIdx.x;
    const int ebeg = bukBase[b], eend = bukBase[b + 1];
    if (threadIdx.x < BKT) hist[threadIdx.x] = 0;
    __syncthreads();
    for (int i = ebeg + threadIdx.x; i < eend; i += 256)
        atomicAdd(&hist[part[i] & (BKT - 1)], 1);
    __syncthreads();
    if (threadIdx.x < 64) {
        const int lane = threadIdx.x;
        int c = hist[lane];
        int x = c;
        #pragma unroll
        for (int off = 1; off < 64; off <<= 1) { int y = __shfl_up(x, off); if (lane >= off) x += y; }
        int excl = x - c;
        cursor[lane] = excl;
        int node = b * BKT + lane;
        if (node < n) {
            rowptr[node] = ebeg + excl;
            dinv[node]   = rsqrtf((float)c + 1.0f);
        }
    }
    if (b == 0 && threadIdx.x == 0) rowptr[n] = e;
    __syncthreads();
    for (int i = ebeg + threadIdx.x; i < eend; i += 256) {
        int p = part[i];
        int pos = atomicAdd(&cursor[p & (BKT - 1)], 1);  // LDS atomic
        int s = p >> 6;
        if (pos < DCAP) loc[pos] = s;
        else colarr[ebeg + pos] = s;   // statistically unreachable overflow path
    }
    __syncthreads();
    const int cnt = min(eend - ebeg, DCAP);
    for (int i = threadIdx.x; i < cnt; i += 256) colarr[ebeg + i] = loc[i];
}

// xs[i,c] = x[i,c] * dinv[i]
__global__ void xscale_kernel(const float* __restrict__ x, const float* __restrict__ dinv,
                              float* __restrict__ xs, int n) {
    int i = blockIdx.x * 256 + threadIdx.x;
    if (i >= n * 6) return;
    xs[i] = x[i] * dinv[i / 6];
}

// ax[i] = dinv[i] * ( sum_{s in N(i)} xs[s] + xs[i] )    (6-dim)
__global__ void aggx_kernel(const float* __restrict__ xs, const int* __restrict__ rowptr,
                            const int* __restrict__ colarr, const float* __restrict__ dinv,
                            float* __restrict__ ax, int n) {
    int i = blockIdx.x * 256 + threadIdx.x;
    if (i >= n) return;
    float a0 = 0, a1 = 0, a2 = 0, a3 = 0, a4 = 0, a5 = 0;
    int beg = rowptr[i], end = rowptr[i + 1];
    for (int e = beg; e < end; ++e) {
        int s = __builtin_nontemporal_load(&colarr[e]);
        const float* xr = xs + (size_t)s * 6;
        a0 += xr[0]; a1 += xr[1]; a2 += xr[2];
        a3 += xr[3]; a4 += xr[4]; a5 += xr[5];
    }
    const float* xi = xs + (size_t)i * 6;
    float di = dinv[i];
    float* o = ax + (size_t)i * 6;
    o[0] = (a0 + xi[0]) * di;
    o[1] = (a1 + xi[1]) * di;
    o[2] = (a2 + xi[2]) * di;
    o[3] = (a3 + xi[3]) * di;
    o[4] = (a4 + xi[4]) * di;
    o[5] = (a5 + xi[5]) * di;
}

// round-to-nearest-even f32 -> bf16
__device__ __forceinline__ unsigned short f2bf(float f) {
    unsigned u = __float_as_uint(f);
    return (unsigned short)((u + 0x7fffu + ((u >> 16) & 1u)) >> 16);
}
__device__ __forceinline__ float bf2f(unsigned short b) {
    return __uint_as_float((unsigned)b << 16);
}

// h1 = bf16( relu(ax @ W1 + b1) )   (6 -> 128); thread = one (node, col)
__global__ __launch_bounds__(256) void gemm1_kernel(const float* __restrict__ ax,
                                                    const float* __restrict__ W1,
                                                    const float* __restrict__ b1,
                                                    unsigned short* __restrict__ h1, int n) {
    __shared__ float Wl[6 * 128];
    __shared__ float bl[128];
    for (int i = threadIdx.x; i < 6 * 128; i += 256) Wl[i] = W1[i];
    if (threadIdx.x < 128) bl[threadIdx.x] = b1[threadIdx.x];
    __syncthreads();
    int gid = blockIdx.x * 256 + threadIdx.x;
    int node = gid >> 7, c = gid & 127;
    if (node >= n) return;
    const float* ar = ax + (size_t)node * 6;
    float acc = bl[c];
    #pragma unroll
    for (int k = 0; k < 6; ++k) acc += ar[k] * Wl[k * 128 + c];
    h1[(size_t)node * 128 + c] = f2bf(fmaxf(acc, 0.0f));
}

// both W2,W3 (f32 [128][128]) -> transposed bf16 [col][k] padded WTP
__global__ void wconv_kernel(const float* __restrict__ W2, unsigned short* __restrict__ wtg2,
                             const float* __restrict__ W3, unsigned short* __restrict__ wtg3) {
    int gid = blockIdx.x * 256 + threadIdx.x;
    const float* W = (gid < 128 * 128) ? W2 : W3;
    unsigned short* wtg = (gid < 128 * 128) ? wtg2 : wtg3;
    int idx = gid & (128 * 128 - 1);
    int k = idx >> 7, c = idx & 127;
    wtg[c * WTP + k] = f2bf(W[idx]);
}

// gout[node,:] = fp8( (hb[node,:] @ W) * dinv[node] )   via bf16 MFMA
// block = 256 threads = 4 waves; wave -> 16 nodes x 128 cols; K=128.
#define MB 64   // nodes per block
__global__ __launch_bounds__(256) void gemm128_mfma(const unsigned short* __restrict__ hb,
                                                    const unsigned short* __restrict__ wtg,
                                                    const float* __restrict__ dinv,
                                                    int* __restrict__ gout, int n) {
    __shared__ unsigned short Wt[128 * WTP];   // 34.8 KB, transposed W
    __shared__ float dl[MB];
    __shared__ float ctile[4][16][16];         // per-wave epilogue repack
    const int tid = threadIdx.x;
    const int node0 = blockIdx.x * MB;
    {   // stage Wt: straight 16B copies (wtg already transposed+padded)
        const int4* s4 = (const int4*)wtg;
        int4* d4 = (int4*)Wt;
        for (int i = tid; i < 128 * WTP * 2 / 16; i += 256) d4[i] = s4[i];
    }
    if (tid < MB) {
        int node = node0 + tid;
        dl[tid] = (node < n) ? dinv[node] : 0.f;
    }
    __syncthreads();
    const int wid  = tid >> 6, lane = tid & 63;
    const int wn0  = node0 + wid * 16;          // this wave's 16 nodes
    const int arow = wn0 + (lane & 15);         // A row for this lane (hb has slack)
    const int koff = (lane >> 4) * 8;           // k-chunk within 32
    bf16x8 a0 = *(const bf16x8*)(hb + (size_t)arow * 128 +  0 + koff);
    bf16x8 a1 = *(const bf16x8*)(hb + (size_t)arow * 128 + 32 + koff);
    bf16x8 a2 = *(const bf16x8*)(hb + (size_t)arow * 128 + 64 + koff);
    bf16x8 a3 = *(const bf16x8*)(hb + (size_t)arow * 128 + 96 + koff);
    const int ccol = lane & 15;
    float* ct = &ctile[wid][0][0];
    #pragma unroll
    for (int nt = 0; nt < 8; ++nt) {            // 16-col output tiles
        const unsigned short* wb = Wt + (size_t)(nt * 16 + (lane & 15)) * WTP + koff;
        f32x4 c = {0.f, 0.f, 0.f, 0.f};
        c = __builtin_amdgcn_mfma_f32_16x16x32_bf16(a0, *(const bf16x8*)(wb +  0), c, 0, 0, 0);
        c = __builtin_amdgcn_mfma_f32_16x16x32_bf16(a1, *(const bf16x8*)(wb + 32), c, 0, 0, 0);
        c = __builtin_amdgcn_mfma_f32_16x16x32_bf16(a2, *(const bf16x8*)(wb + 64), c, 0, 0, 0);
        c = __builtin_amdgcn_mfma_f32_16x16x32_bf16(a3, *(const bf16x8*)(wb + 96), c, 0, 0, 0);
        #pragma unroll
        for (int r = 0; r < 4; ++r) {
            int row = (lane >> 4) * 4 + r;
            ct[row * 16 + ccol] = c[r] * dl[wid * 16 + row];
        }
        int rrow = lane >> 2, rdw = lane & 3;
        f32x4 v = *(const f32x4*)&ct[rrow * 16 + rdw * 4];
        int w = __builtin_amdgcn_cvt_pk_fp8_f32(v[0], v[1], 0, false);
        w     = __builtin_amdgcn_cvt_pk_fp8_f32(v[2], v[3], w, true);
        int onode = wn0 + rrow;
        if (onode < n) gout[(size_t)onode * 32 + nt * 4 + rdw] = w;
    }
}

// out[i] = bf16( relu_opt( dinv[i]*( sum_{s in N(i)} g[s] + g[i] ) + b ) )  (fp8 g)
// R10: 8 lanes/row x dwordx4 -> 8 edges per gather instruction; 32 edges/iter.
// Lane L: edge-group eg=L>>3, col-slot cs=L&7 (fp8 cols cs*16..+15).
__global__ __launch_bounds__(256) void agg128_kernel(const void* __restrict__ g,
                                                     const int* __restrict__ rowptr,
                                                     const int* __restrict__ colarr,
                                                     const float* __restrict__ dinv,
                                                     const float* __restrict__ bias,
                                                     unsigned short* __restrict__ out,
                                                     int n, int relu) {
    int node = blockIdx.x * 4 + (threadIdx.x >> 6);
    if (node >= n) return;
    const int lane = threadIdx.x & 63;
    const int eg = lane >> 3;          // edge group 0..7
    const int cs = lane & 7;           // dword-quad slot within row
    const int* gi = (const int*)g;     // row s -> gi[s*32 + cs*4 .. +3]
    const int beg = rowptr[node], end = rowptr[node + 1];
    float ac[16];
    #pragma unroll
    for (int j = 0; j < 16; ++j) ac[j] = 0.f;

    #define ADD4(vv)                                                           \
    {                                                                          \
        f32x2 p;                                                               \
        p = __builtin_amdgcn_cvt_pk_f32_fp8((vv).x, false); ac[0] += p[0]; ac[1] += p[1]; \
        p = __builtin_amdgcn_cvt_pk_f32_fp8((vv).x, true);  ac[2] += p[0]; ac[3] += p[1]; \
        p = __builtin_amdgcn_cvt_pk_f32_fp8((vv).y, false); ac[4] += p[0]; ac[5] += p[1]; \
        p = __builtin_amdgcn_cvt_pk_f32_fp8((vv).y, true);  ac[6] += p[0]; ac[7] += p[1]; \
        p = __builtin_amdgcn_cvt_pk_f32_fp8((vv).z, false); ac[8] += p[0]; ac[9] += p[1]; \
        p = __builtin_amdgcn_cvt_pk_f32_fp8((vv).z, true);  ac[10] += p[0]; ac[11] += p[1]; \
        p = __builtin_amdgcn_cvt_pk_f32_fp8((vv).w, false); ac[12] += p[0]; ac[13] += p[1]; \
        p = __builtin_amdgcn_cvt_pk_f32_fp8((vv).w, true);  ac[14] += p[0]; ac[15] += p[1]; \
    }

    int e = beg;
    // main: 32 edges/iter, 4 dwordx4 gathers in flight, no guards
    for (; e + 32 <= end; e += 32) {
        int s0 = __builtin_nontemporal_load(&colarr[e      + eg]);
        int s1 = __builtin_nontemporal_load(&colarr[e +  8 + eg]);
        int s2 = __builtin_nontemporal_load(&colarr[e + 16 + eg]);
        int s3 = __builtin_nontemporal_load(&colarr[e + 24 + eg]);
        int4 v0 = *(const int4*)(gi + (size_t)s0 * 32 + cs * 4);
        int4 v1 = *(const int4*)(gi + (size_t)s1 * 32 + cs * 4);
        int4 v2 = *(const int4*)(gi + (size_t)s2 * 32 + cs * 4);
        int4 v3 = *(const int4*)(gi + (size_t)s3 * 32 + cs * 4);
        ADD4(v0); ADD4(v1); ADD4(v2); ADD4(v3);
    }
    // tail: 8 edges/iter, guarded
    for (; e < end; e += 8) {
        int idx = e + eg;
        int4 v = make_int4(0, 0, 0, 0);
        if (idx < end) {
            int s = colarr[idx];
            v = *(const int4*)(gi + (size_t)s * 32 + cs * 4);
        }
        ADD4(v);
    }
    // self term: count once (group 0 only)
    if (eg == 0) {
        int4 v = *(const int4*)(gi + (size_t)node * 32 + cs * 4);
        ADD4(v);
    }
    #undef ADD4
    // reduce across the 8 edge groups (lanes with equal cs)
    #pragma unroll
    for (int off = 8; off <= 32; off <<= 1) {
        #pragma unroll
        for (int j = 0; j < 16; ++j) ac[j] += __shfl_xor(ac[j], off);
    }
    if (eg == 0) {
        float di = dinv[node];
        const float4* bp = (const float4*)(bias + cs * 16);
        unsigned int w[8];
        #pragma unroll
        for (int q = 0; q < 4; ++q) {
            float4 b = bp[q];
            float o0 = ac[q * 4 + 0] * di + b.x;
            float o1 = ac[q * 4 + 1] * di + b.y;
            float o2 = ac[q * 4 + 2] * di + b.z;
            float o3 = ac[q * 4 + 3] * di + b.w;
            if (relu) {
                o0 = fmaxf(o0, 0.f); o1 = fmaxf(o1, 0.f);
                o2 = fmaxf(o2, 0.f); o3 = fmaxf(o3, 0.f);
            }
            w[q * 2 + 0] = (unsigned)f2bf(o0) | ((unsigned)f2bf(o1) << 16);
            w[q * 2 + 1] = (unsigned)f2bf(o2) | ((unsigned)f2bf(o3) << 16);
        }
        int* op = (int*)(out + (size_t)node * 128 + cs * 16);
        i32x4 w0 = { (int)w[0], (int)w[1], (int)w[2], (int)w[3] };
        i32x4 w1 = { (int)w[4], (int)w[5], (int)w[6], (int)w[7] };
        __builtin_nontemporal_store(w0, (i32x4*)op);
        __builtin_nontemporal_store(w1, (i32x4*)(op + 4));
    }
}

// t[i] = dot(hb[i,:], W4[:,0]) * dinv[i]   (hb bf16)
__global__ void head_kernel(const unsigned short* __restrict__ hb,
                            const float* __restrict__ W4,
                            const float* __restrict__ dinv, float* __restrict__ t, int n) {
    int node = blockIdx.x * 4 + (threadIdx.x >> 6);
    if (node >= n) return;
    int lane = threadIdx.x & 63;
    ushort2 v = ((const ushort2*)(hb + (size_t)node * 128))[lane];
    float2 w = ((const float2*)W4)[lane];
    float p = bf2f(v.x) * w.x + bf2f(v.y) * w.y;
    #pragma unroll
    for (int off = 32; off; off >>= 1) p += __shfl_xor(p, off);
    if (lane == 0) t[node] = p * dinv[node];
}

// s[i] = dinv[i]*( sum t[s] + t[i] ) + b4
__global__ void aggs_kernel(const float* __restrict__ t, const int* __restrict__ rowptr,
                            const int* __restrict__ colarr, const float* __restrict__ dinv,
                            const float* __restrict__ b4, float* __restrict__ s, int n) {
    int i = blockIdx.x * 256 + threadIdx.x;
    if (i >= n) return;
    float acc = 0.f;
    int beg = rowptr[i], end = rowptr[i + 1];
    int e = beg;
    for (; e + 3 < end; e += 4) {
        int c0 = __builtin_nontemporal_load(&colarr[e]);
        int c1 = __builtin_nontemporal_load(&colarr[e + 1]);
        int c2 = __builtin_nontemporal_load(&colarr[e + 2]);
        int c3 = __builtin_nontemporal_load(&colarr[e + 3]);
        acc += (t[c0] + t[c1]) + (t[c2] + t[c3]);
    }
    for (; e < end; ++e) acc += t[colarr[e]];
    s[i] = (acc + t[i]) * dinv[i] + b4[0];
}

// batch is sorted: record each graph's node range
__global__ void bounds_kernel(const int* __restrict__ batch, int* __restrict__ gstart,
                              int* __restrict__ gend, int n) {
    int i = blockIdx.x * 256 + threadIdx.x;
    if (i >= n) return;
    int g = batch[i];
    if (i == 0     || batch[i - 1] != g) gstart[g] = i;
    if (i == n - 1 || batch[i + 1] != g) gend[g]   = i + 1;
}

// one wave per graph: mean over its node range + sigmoid, straight to d_out
__global__ void pool2_kernel(const float* __restrict__ sv, const int* __restrict__ gstart,
                             const int* __restrict__ gend, float* __restrict__ out, int ng) {
    int g = blockIdx.x * 4 + (threadIdx.x >> 6);
    if (g >= ng) return;
    int lane = threadIdx.x & 63;
    int beg = gstart[g], end = gend[g];
    float acc = 0.f;
    for (int i = beg + lane; i < end; i += 64) acc += sv[i];
    #pragma unroll
    for (int off = 32; off; off >>= 1) acc += __shfl_xor(acc, off);
    if (lane == 0) {
        float c = fmaxf((float)(end - beg), 1.0f);
        float v = acc / c;
        out[g] = 1.0f / (1.0f + expf(-v));
    }
}

extern "C" void kernel_launch(void* const* d_in, const int* in_sizes, int n_in,
                              void* d_out, int out_size, void* d_ws, size_t ws_size,
                              hipStream_t stream) {
    const float* x    = (const float*)d_in[0];
    const int*   eidx = (const int*)d_in[1];
    const int*   batch= (const int*)d_in[2];
    const float* W1 = (const float*)d_in[3];
    const float* b1 = (const float*)d_in[4];
    const float* W2 = (const float*)d_in[5];
    const float* b2 = (const float*)d_in[6];
    const float* W3 = (const float*)d_in[7];
    const float* b3 = (const float*)d_in[8];
    const float* W4 = (const float*)d_in[9];
    const float* b4 = (const float*)d_in[10];

    const int n  = in_sizes[0] / 6;
    const int e  = in_sizes[1] / 2;
    const int ng = out_size;
    const int* src = eidx;
    const int* dst = eidx + e;
    const int nbuk = (n + BKT - 1) / BKT;   // 1563 @ n=100k (MAXBUK cap)

    // workspace layout
    char* ws = (char*)d_ws;
    float* bufA   = (float*)ws; ws += (size_t)n * 128 * 4;   // xs / CSR scratch / hb
    void*  gbuf   = (void*)ws;  ws += (size_t)n * 128 * 4;   // ax / fp8 gout
    int*   colarr = (int*)ws;   ws += (size_t)e * 4;
    int*   rowptr = (int*)ws;   ws += ((size_t)n + 4) * 4;
    float* dinv   = (float*)ws; ws += (size_t)n * 4;
    float* t      = (float*)ws; ws += (size_t)n * 4;
    float* sv     = (float*)ws; ws += (size_t)n * 4;
    int*   gstart = (int*)ws;   ws += 1024;
    int*   gend   = (int*)ws;   ws += 1024;
    unsigned short* wtg2 = (unsigned short*)ws; ws += 128 * WTP * 2;
    unsigned short* wtg3 = (unsigned short*)ws; ws += 128 * WTP * 2;

    // CSR-build scratch in bufA's tail (dead before gemm1 writes hb there)
    char* tail = (char*)bufA;
    int* part    = (int*)(tail + (16u << 20));   // e ints (6.4MB)
    int* hmatT   = (int*)(tail + (24u << 20));   // nbuk*NCH ints
    int* totals  = (int*)(tail + (26u << 20));   // nbuk ints
    int* bukBase = (int*)(tail + (27u << 20));   // nbuk+1 ints

    float* xs = bufA;                       // [n,6] prescaled x
    float* ax = (float*)gbuf;               // [n,6] aggregated
    unsigned short* hb = (unsigned short*)bufA;  // [n,128] bf16 h

    const int nb = (n + 255) / 256;
    const int nw = (n + 3) / 4;
    const int gb = (n + MB - 1) / MB;

    // ---- CSR build (no device-scope atomics) ----
    hist_bucket<<<NCH, 256, 0, stream>>>(dst, hmatT, e, nbuk);
    scan_chunks<<<(nbuk + 3) / 4, 256, 0, stream>>>(hmatT, totals, nbuk);
    scan_kernel<<<1, 1024, 0, stream>>>(totals, bukBase, nbuk);
    partition_kernel<<<NCH, 256, 0, stream>>>(src, dst, hmatT, bukBase, part, e, nbuk);
    bucket_csr<<<nbuk, 256, 0, stream>>>(part, bukBase, colarr, rowptr, dinv, n, e);

    // ---- weight prep (both layers, one launch) ----
    wconv_kernel<<<128, 256, 0, stream>>>(W2, wtg2, W3, wtg3);

    // ---- layer 1: prescale x, aggregate (6-dim), then GEMM -> bf16 h ----
    xscale_kernel<<<(n * 6 + 255) / 256, 256, 0, stream>>>(x, dinv, xs, n);
    aggx_kernel<<<nb, 256, 0, stream>>>(xs, rowptr, colarr, dinv, ax, n);
    gemm1_kernel<<<(n * 128 + 255) / 256, 256, 0, stream>>>(ax, W1, b1, hb, n);

    // ---- layer 2 ----
    gemm128_mfma<<<gb, 256, 0, stream>>>(hb, wtg2, dinv, (int*)gbuf, n);
    agg128_kernel<<<nw, 256, 0, stream>>>(gbuf, rowptr, colarr, dinv, b2, hb, n, 1);

    // ---- layer 3 ----
    gemm128_mfma<<<gb, 256, 0, stream>>>(hb, wtg3, dinv, (int*)gbuf, n);
    agg128_kernel<<<nw, 256, 0, stream>>>(gbuf, rowptr, colarr, dinv, b3, hb, n, 1);

    // ---- layer 4: project to scalar, aggregate ----
    head_kernel<<<nw, 256, 0, stream>>>(hb, W4, dinv, t, n);
    aggs_kernel<<<nb, 256, 0, stream>>>(t, rowptr, colarr, dinv, b4, sv, n);

    // ---- pool: sorted batch -> segment bounds + per-graph wave mean ----
    hipMemsetAsync(gstart, 0, 2048, stream);
    bounds_kernel<<<nb, 256, 0, stream>>>(batch, gstart, gend, n);
    pool2_kernel<<<(ng + 3) / 4, 256, 0, stream>>>(sv, gstart, gend, (float*)d_out, ng);
}

// Round 12
// 280.597 us; speedup vs baseline: 1.4402x; 1.4402x over previous
//
#include <hip/hip_runtime.h>
#include <math.h>

// ---------------------------------------------------------------------------
// SimpleGNN (4-layer GCN + mean pool + sigmoid) on MI355X.
//   - CSR build: atomic-free bucket sort (R6).
//   - norm factored into GEMM epilogue; aggregation = pure gather-sum
//   - h in BF16; layers 2,3 = bf16 MFMA GEMM (16x16x32) -> FP8 gather buffer.
//   - agg128 (R12): R9 structure (2 edges/wave x dword, 4-gather unroll).
//     Mean degree = 16 (R11 lesson: 32-edge loop never ran -> serial tail;
//     VGPR 48 halved occupancy). Tail = ONE masked 8-edge block so tail
//     edges keep 4-deep MLP (masked slots gather node's own row, cndmask'd).
//   - layer1 reassociated (aggregate 6-dim x first); layer4 projected to
//     scalar first; pool via sorted-batch segment bounds + wave reduce
// ---------------------------------------------------------------------------

typedef float f32x2 __attribute__((ext_vector_type(2)));
typedef float f32x4 __attribute__((ext_vector_type(4)));
typedef short bf16x8 __attribute__((ext_vector_type(8)));   // 8 bf16 = 4 VGPRs

#define BKT    64     // nodes per bucket (shift 6)
#define NCH    128    // edge chunks
#define MAXBUK 2048   // LDS bucket counters (nbuk = 1563 @ n=100k)
#define DCAP   2048   // per-bucket LDS colarr staging
#define WTP    136    // padded row length of transposed W (bf16)

// ---- CSR pass A: per-chunk LDS histogram over buckets ----
__global__ __launch_bounds__(256) void hist_bucket(const int* __restrict__ dst,
                                                   int* __restrict__ hmatT,
                                                   int e, int nbuk) {
    __shared__ int h[MAXBUK];
    for (int i = threadIdx.x; i < nbuk; i += 256) h[i] = 0;
    __syncthreads();
    const int per = (e + NCH - 1) / NCH;
    const int beg = blockIdx.x * per;
    const int end = min(beg + per, e);
    for (int i = beg + threadIdx.x; i < end; i += 256)
        atomicAdd(&h[dst[i] >> 6], 1);          // LDS atomic
    __syncthreads();
    for (int b = threadIdx.x; b < nbuk; b += 256)
        hmatT[b * NCH + blockIdx.x] = h[b];
}

// ---- CSR pass B1: per-bucket exclusive scan over its NCH chunk-counts ----
__global__ __launch_bounds__(256) void scan_chunks(int* __restrict__ hmatT,
                                                   int* __restrict__ totals, int nbuk) {
    int b = blockIdx.x * 4 + (threadIdx.x >> 6);
    if (b >= nbuk) return;
    const int lane = threadIdx.x & 63;
    int* row = hmatT + b * NCH;
    int v0 = row[lane], v1 = row[64 + lane];
    int x = v0;
    #pragma unroll
    for (int off = 1; off < 64; off <<= 1) { int y = __shfl_up(x, off); if (lane >= off) x += y; }
    int carry = __shfl(x, 63);
    int e0 = x - v0;
    int x1 = v1;
    #pragma unroll
    for (int off = 1; off < 64; off <<= 1) { int y = __shfl_up(x1, off); if (lane >= off) x1 += y; }
    int e1 = x1 - v1 + carry;
    int tot = __shfl(x1, 63) + carry;
    row[lane] = e0;
    row[64 + lane] = e1;
    if (lane == 0) totals[b] = tot;
}

// ---- CSR pass B2: single-block chunked exclusive scan ----
__global__ void scan_kernel(const int* __restrict__ counts, int* __restrict__ rowptr, int n) {
    __shared__ int wsum[16];
    __shared__ int carry_s;
    const int tid  = threadIdx.x;            // 1024 threads
    const int lane = tid & 63, wid = tid >> 6;
    if (tid == 0) carry_s = 0;
    __syncthreads();
    const int nchunk = (n + 4095) >> 12;
    for (int c = 0; c < nchunk; ++c) {
        int i0 = (c << 12) + tid * 4;
        int4 v = make_int4(0, 0, 0, 0);
        if (i0 + 3 < n) {
            v = *(const int4*)(counts + i0);
        } else {
            if (i0     < n) v.x = counts[i0];
            if (i0 + 1 < n) v.y = counts[i0 + 1];
            if (i0 + 2 < n) v.z = counts[i0 + 2];
            if (i0 + 3 < n) v.w = counts[i0 + 3];
        }
        int s1 = v.x, s2 = s1 + v.y, s3 = s2 + v.z, s4 = s3 + v.w;
        int x = s4;
        #pragma unroll
        for (int off = 1; off < 64; off <<= 1) {
            int y = __shfl_up(x, off);
            if (lane >= off) x += y;
        }
        if (lane == 63) wsum[wid] = x;
        __syncthreads();
        if (wid == 0) {
            int s = (lane < 16) ? wsum[lane] : 0;
            #pragma unroll
            for (int off = 1; off < 16; off <<= 1) {
                int y = __shfl_up(s, off);
                if (lane >= off) s += y;
            }
            if (lane < 16) wsum[lane] = s;
        }
        __syncthreads();
        int carry = carry_s + ((wid > 0) ? wsum[wid - 1] : 0);
        int excl  = carry + x - s4;
        if (i0     < n) rowptr[i0 + 1] = excl + s1;
        if (i0 + 1 < n) rowptr[i0 + 2] = excl + s2;
        if (i0 + 2 < n) rowptr[i0 + 3] = excl + s3;
        if (i0 + 3 < n) rowptr[i0 + 4] = excl + s4;
        __syncthreads();
        if (tid == 1023) carry_s = carry + x;
        __syncthreads();
    }
    if (tid == 0) rowptr[0] = 0;
}

// ---- CSR pass C: partition edges into bucket-grouped order ----
__global__ __launch_bounds__(256) void partition_kernel(const int* __restrict__ src,
                                                        const int* __restrict__ dst,
                                                        const int* __restrict__ hmatT,
                                                        const int* __restrict__ bukBase,
                                                        int* __restrict__ part,
                                                        int e, int nbuk) {
    __shared__ int cur[MAXBUK];
    for (int b = threadIdx.x; b < nbuk; b += 256)
        cur[b] = bukBase[b] + hmatT[b * NCH + blockIdx.x];
    __syncthreads();
    const int per = (e + NCH - 1) / NCH;
    const int beg = blockIdx.x * per;
    const int end = min(beg + per, e);
    for (int i = beg + threadIdx.x; i < end; i += 256) {
        int d = dst[i], s = src[i];
        int pos = atomicAdd(&cur[d >> 6], 1);   // LDS atomic
        part[pos] = (d & 63) | (s << 6);        // s < 2^17 -> fits
    }
}

// ---- CSR pass D: per-bucket local CSR finish + fused dinv ----
__global__ __launch_bounds__(256) void bucket_csr(const int* __restrict__ part,
                                                  const int* __restrict__ bukBase,
                                                  int* __restrict__ colarr,
                                                  int* __restrict__ rowptr,
                                                  float* __restrict__ dinv,
                                                  int n, int e) {
    __shared__ int hist[BKT];
    __shared__ int cursor[BKT];
    __shared__ int loc[DCAP];
    const int b = blockIdx.x;
    const int ebeg = bukBase[b], eend = bukBase[b + 1];
    if (threadIdx.x < BKT) hist[threadIdx.x] = 0;
    __syncthreads();
    for (int i = ebeg + threadIdx.x; i < eend; i += 256)
        atomicAdd(&hist[part[i] & (BKT - 1)], 1);
    __syncthreads();
    if (threadIdx.x < 64) {
        const int lane = threadIdx.x;
        int c = hist[lane];
        int x = c;
        #pragma unroll
        for (int off = 1; off < 64; off <<= 1) { int y = __shfl_up(x, off); if (lane >= off) x += y; }
        int excl = x - c;
        cursor[lane] = excl;
        int node = b * BKT + lane;
        if (node < n) {
            rowptr[node] = ebeg + excl;
            dinv[node]   = rsqrtf((float)c + 1.0f);
        }
    }
    if (b == 0 && threadIdx.x == 0) rowptr[n] = e;
    __syncthreads();
    for (int i = ebeg + threadIdx.x; i < eend; i += 256) {
        int p = part[i];
        int pos = atomicAdd(&cursor[p & (BKT - 1)], 1);  // LDS atomic
        int s = p >> 6;
        if (pos < DCAP) loc[pos] = s;
        else colarr[ebeg + pos] = s;   // statistically unreachable overflow path
    }
    __syncthreads();
    const int cnt = min(eend - ebeg, DCAP);
    for (int i = threadIdx.x; i < cnt; i += 256) colarr[ebeg + i] = loc[i];
}

// xs[i,c] = x[i,c] * dinv[i]
__global__ void xscale_kernel(const float* __restrict__ x, const float* __restrict__ dinv,
                              float* __restrict__ xs, int n) {
    int i = blockIdx.x * 256 + threadIdx.x;
    if (i >= n * 6) return;
    xs[i] = x[i] * dinv[i / 6];
}

// ax[i] = dinv[i] * ( sum_{s in N(i)} xs[s] + xs[i] )    (6-dim)
__global__ void aggx_kernel(const float* __restrict__ xs, const int* __restrict__ rowptr,
                            const int* __restrict__ colarr, const float* __restrict__ dinv,
                            float* __restrict__ ax, int n) {
    int i = blockIdx.x * 256 + threadIdx.x;
    if (i >= n) return;
    float a0 = 0, a1 = 0, a2 = 0, a3 = 0, a4 = 0, a5 = 0;
    int beg = rowptr[i], end = rowptr[i + 1];
    for (int e = beg; e < end; ++e) {
        int s = colarr[e];
        const float* xr = xs + (size_t)s * 6;
        a0 += xr[0]; a1 += xr[1]; a2 += xr[2];
        a3 += xr[3]; a4 += xr[4]; a5 += xr[5];
    }
    const float* xi = xs + (size_t)i * 6;
    float di = dinv[i];
    float* o = ax + (size_t)i * 6;
    o[0] = (a0 + xi[0]) * di;
    o[1] = (a1 + xi[1]) * di;
    o[2] = (a2 + xi[2]) * di;
    o[3] = (a3 + xi[3]) * di;
    o[4] = (a4 + xi[4]) * di;
    o[5] = (a5 + xi[5]) * di;
}

// round-to-nearest-even f32 -> bf16
__device__ __forceinline__ unsigned short f2bf(float f) {
    unsigned u = __float_as_uint(f);
    return (unsigned short)((u + 0x7fffu + ((u >> 16) & 1u)) >> 16);
}
__device__ __forceinline__ float bf2f(unsigned short b) {
    return __uint_as_float((unsigned)b << 16);
}

// h1 = bf16( relu(ax @ W1 + b1) )   (6 -> 128); thread = one (node, col)
__global__ __launch_bounds__(256) void gemm1_kernel(const float* __restrict__ ax,
                                                    const float* __restrict__ W1,
                                                    const float* __restrict__ b1,
                                                    unsigned short* __restrict__ h1, int n) {
    __shared__ float Wl[6 * 128];
    __shared__ float bl[128];
    for (int i = threadIdx.x; i < 6 * 128; i += 256) Wl[i] = W1[i];
    if (threadIdx.x < 128) bl[threadIdx.x] = b1[threadIdx.x];
    __syncthreads();
    int gid = blockIdx.x * 256 + threadIdx.x;
    int node = gid >> 7, c = gid & 127;
    if (node >= n) return;
    const float* ar = ax + (size_t)node * 6;
    float acc = bl[c];
    #pragma unroll
    for (int k = 0; k < 6; ++k) acc += ar[k] * Wl[k * 128 + c];
    h1[(size_t)node * 128 + c] = f2bf(fmaxf(acc, 0.0f));
}

// both W2,W3 (f32 [128][128]) -> transposed bf16 [col][k] padded WTP
__global__ void wconv_kernel(const float* __restrict__ W2, unsigned short* __restrict__ wtg2,
                             const float* __restrict__ W3, unsigned short* __restrict__ wtg3) {
    int gid = blockIdx.x * 256 + threadIdx.x;
    const float* W = (gid < 128 * 128) ? W2 : W3;
    unsigned short* wtg = (gid < 128 * 128) ? wtg2 : wtg3;
    int idx = gid & (128 * 128 - 1);
    int k = idx >> 7, c = idx & 127;
    wtg[c * WTP + k] = f2bf(W[idx]);
}

// gout[node,:] = fp8( (hb[node,:] @ W) * dinv[node] )   via bf16 MFMA
// block = 256 threads = 4 waves; wave -> 16 nodes x 128 cols; K=128.
#define MB 64   // nodes per block
__global__ __launch_bounds__(256) void gemm128_mfma(const unsigned short* __restrict__ hb,
                                                    const unsigned short* __restrict__ wtg,
                                                    const float* __restrict__ dinv,
                                                    int* __restrict__ gout, int n) {
    __shared__ unsigned short Wt[128 * WTP];   // 34.8 KB, transposed W
    __shared__ float dl[MB];
    __shared__ float ctile[4][16][16];         // per-wave epilogue repack
    const int tid = threadIdx.x;
    const int node0 = blockIdx.x * MB;
    {   // stage Wt: straight 16B copies (wtg already transposed+padded)
        const int4* s4 = (const int4*)wtg;
        int4* d4 = (int4*)Wt;
        for (int i = tid; i < 128 * WTP * 2 / 16; i += 256) d4[i] = s4[i];
    }
    if (tid < MB) {
        int node = node0 + tid;
        dl[tid] = (node < n) ? dinv[node] : 0.f;
    }
    __syncthreads();
    const int wid  = tid >> 6, lane = tid & 63;
    const int wn0  = node0 + wid * 16;          // this wave's 16 nodes
    const int arow = wn0 + (lane & 15);         // A row for this lane (hb has slack)
    const int koff = (lane >> 4) * 8;           // k-chunk within 32
    bf16x8 a0 = *(const bf16x8*)(hb + (size_t)arow * 128 +  0 + koff);
    bf16x8 a1 = *(const bf16x8*)(hb + (size_t)arow * 128 + 32 + koff);
    bf16x8 a2 = *(const bf16x8*)(hb + (size_t)arow * 128 + 64 + koff);
    bf16x8 a3 = *(const bf16x8*)(hb + (size_t)arow * 128 + 96 + koff);
    const int ccol = lane & 15;
    float* ct = &ctile[wid][0][0];
    #pragma unroll
    for (int nt = 0; nt < 8; ++nt) {            // 16-col output tiles
        const unsigned short* wb = Wt + (size_t)(nt * 16 + (lane & 15)) * WTP + koff;
        f32x4 c = {0.f, 0.f, 0.f, 0.f};
        c = __builtin_amdgcn_mfma_f32_16x16x32_bf16(a0, *(const bf16x8*)(wb +  0), c, 0, 0, 0);
        c = __builtin_amdgcn_mfma_f32_16x16x32_bf16(a1, *(const bf16x8*)(wb + 32), c, 0, 0, 0);
        c = __builtin_amdgcn_mfma_f32_16x16x32_bf16(a2, *(const bf16x8*)(wb + 64), c, 0, 0, 0);
        c = __builtin_amdgcn_mfma_f32_16x16x32_bf16(a3, *(const bf16x8*)(wb + 96), c, 0, 0, 0);
        #pragma unroll
        for (int r = 0; r < 4; ++r) {
            int row = (lane >> 4) * 4 + r;
            ct[row * 16 + ccol] = c[r] * dl[wid * 16 + row];
        }
        int rrow = lane >> 2, rdw = lane & 3;
        f32x4 v = *(const f32x4*)&ct[rrow * 16 + rdw * 4];
        int w = __builtin_amdgcn_cvt_pk_fp8_f32(v[0], v[1], 0, false);
        w     = __builtin_amdgcn_cvt_pk_fp8_f32(v[2], v[3], w, true);
        int onode = wn0 + rrow;
        if (onode < n) gout[(size_t)onode * 32 + nt * 4 + rdw] = w;
    }
}

// out[i] = bf16( relu_opt( dinv[i]*( sum_{s in N(i)} g[s] + g[i] ) + b ) )  (fp8 g)
// R9 structure: 32 lanes x 1 dword per row, 2 edges/wave (half=lane>>5),
// 4-gather unroll. R12: tail = one MASKED 8-edge block (keeps 4-deep MLP;
// masked slots gather node's own valid row, contribution cndmask'd to 0).
__global__ __launch_bounds__(256) void agg128_kernel(const void* __restrict__ g,
                                                     const int* __restrict__ rowptr,
                                                     const int* __restrict__ colarr,
                                                     const float* __restrict__ dinv,
                                                     const float* __restrict__ bias,
                                                     unsigned short* __restrict__ out,
                                                     int n, int relu) {
    int node = blockIdx.x * 4 + (threadIdx.x >> 6);
    if (node >= n) return;
    const int lane = threadIdx.x & 63;
    const int half = lane >> 5;        // edge-in-pair
    const int c    = lane & 31;        // dword index within row
    const int* gi = (const int*)g;     // row s -> gi[s*32 + c]
    const int beg = rowptr[node], end = rowptr[node + 1];
    float ax = 0.f, ay = 0.f, az = 0.f, aw = 0.f;
    int e = beg;
    // main: 8 edges/iter, 4 gathers in flight, no guards
    for (; e + 8 <= end; e += 8) {
        int s0 = colarr[e     + half];
        int s1 = colarr[e + 2 + half];
        int s2 = colarr[e + 4 + half];
        int s3 = colarr[e + 6 + half];
        int w0 = gi[(size_t)s0 * 32 + c];
        int w1 = gi[(size_t)s1 * 32 + c];
        int w2 = gi[(size_t)s2 * 32 + c];
        int w3 = gi[(size_t)s3 * 32 + c];
        f32x2 l0 = __builtin_amdgcn_cvt_pk_f32_fp8(w0, false);
        f32x2 h0 = __builtin_amdgcn_cvt_pk_f32_fp8(w0, true);
        f32x2 l1 = __builtin_amdgcn_cvt_pk_f32_fp8(w1, false);
        f32x2 h1 = __builtin_amdgcn_cvt_pk_f32_fp8(w1, true);
        f32x2 l2 = __builtin_amdgcn_cvt_pk_f32_fp8(w2, false);
        f32x2 h2 = __builtin_amdgcn_cvt_pk_f32_fp8(w2, true);
        f32x2 l3 = __builtin_amdgcn_cvt_pk_f32_fp8(w3, false);
        f32x2 h3 = __builtin_amdgcn_cvt_pk_f32_fp8(w3, true);
        ax += (l0[0] + l1[0]) + (l2[0] + l3[0]);
        ay += (l0[1] + l1[1]) + (l2[1] + l3[1]);
        az += (h0[0] + h1[0]) + (h2[0] + h3[0]);
        aw += (h0[1] + h1[1]) + (h2[1] + h3[1]);
    }
    // tail: single masked 8-edge block (tail length < 8)
    if (e < end) {
        int i0 = e     + half;
        int i1 = e + 2 + half;
        int i2 = e + 4 + half;
        int i3 = e + 6 + half;
        bool m0 = i0 < end, m1 = i1 < end, m2 = i2 < end, m3 = i3 < end;
        int s0 = m0 ? colarr[i0] : node;    // node's row is always valid
        int s1 = m1 ? colarr[i1] : node;
        int s2 = m2 ? colarr[i2] : node;
        int s3 = m3 ? colarr[i3] : node;
        int w0 = gi[(size_t)s0 * 32 + c];
        int w1 = gi[(size_t)s1 * 32 + c];
        int w2 = gi[(size_t)s2 * 32 + c];
        int w3 = gi[(size_t)s3 * 32 + c];
        f32x2 l0 = __builtin_amdgcn_cvt_pk_f32_fp8(w0, false);
        f32x2 h0 = __builtin_amdgcn_cvt_pk_f32_fp8(w0, true);
        f32x2 l1 = __builtin_amdgcn_cvt_pk_f32_fp8(w1, false);
        f32x2 h1 = __builtin_amdgcn_cvt_pk_f32_fp8(w1, true);
        f32x2 l2 = __builtin_amdgcn_cvt_pk_f32_fp8(w2, false);
        f32x2 h2 = __builtin_amdgcn_cvt_pk_f32_fp8(w2, true);
        f32x2 l3 = __builtin_amdgcn_cvt_pk_f32_fp8(w3, false);
        f32x2 h3 = __builtin_amdgcn_cvt_pk_f32_fp8(w3, true);
        ax += (m0 ? l0[0] : 0.f) + (m1 ? l1[0] : 0.f) + (m2 ? l2[0] : 0.f) + (m3 ? l3[0] : 0.f);
        ay += (m0 ? l0[1] : 0.f) + (m1 ? l1[1] : 0.f) + (m2 ? l2[1] : 0.f) + (m3 ? l3[1] : 0.f);
        az += (m0 ? h0[0] : 0.f) + (m1 ? h1[0] : 0.f) + (m2 ? h2[0] : 0.f) + (m3 ? h3[0] : 0.f);
        aw += (m0 ? h0[1] : 0.f) + (m1 ? h1[1] : 0.f) + (m2 ? h2[1] : 0.f) + (m3 ? h3[1] : 0.f);
    }
    // cross-half reduce: combine the two edge-halves
    ax += __shfl_xor(ax, 32);
    ay += __shfl_xor(ay, 32);
    az += __shfl_xor(az, 32);
    aw += __shfl_xor(aw, 32);
    if (lane < 32) {
        int wsv = gi[(size_t)node * 32 + lane];
        f32x2 slo = __builtin_amdgcn_cvt_pk_f32_fp8(wsv, false);
        f32x2 shi = __builtin_amdgcn_cvt_pk_f32_fp8(wsv, true);
        float4 b = ((const float4*)bias)[lane];
        float di = dinv[node];
        float ox = (ax + slo[0]) * di + b.x;
        float oy = (ay + slo[1]) * di + b.y;
        float oz = (az + shi[0]) * di + b.z;
        float ow = (aw + shi[1]) * di + b.w;
        if (relu) {
            ox = fmaxf(ox, 0.f); oy = fmaxf(oy, 0.f);
            oz = fmaxf(oz, 0.f); ow = fmaxf(ow, 0.f);
        }
        ushort4 o;
        o.x = f2bf(ox); o.y = f2bf(oy); o.z = f2bf(oz); o.w = f2bf(ow);
        ((ushort4*)(out + (size_t)node * 128))[lane] = o;
    }
}

// t[i] = dot(hb[i,:], W4[:,0]) * dinv[i]   (hb bf16)
__global__ void head_kernel(const unsigned short* __restrict__ hb,
                            const float* __restrict__ W4,
                            const float* __restrict__ dinv, float* __restrict__ t, int n) {
    int node = blockIdx.x * 4 + (threadIdx.x >> 6);
    if (node >= n) return;
    int lane = threadIdx.x & 63;
    ushort2 v = ((const ushort2*)(hb + (size_t)node * 128))[lane];
    float2 w = ((const float2*)W4)[lane];
    float p = bf2f(v.x) * w.x + bf2f(v.y) * w.y;
    #pragma unroll
    for (int off = 32; off; off >>= 1) p += __shfl_xor(p, off);
    if (lane == 0) t[node] = p * dinv[node];
}

// s[i] = dinv[i]*( sum t[s] + t[i] ) + b4
__global__ void aggs_kernel(const float* __restrict__ t, const int* __restrict__ rowptr,
                            const int* __restrict__ colarr, const float* __restrict__ dinv,
                            const float* __restrict__ b4, float* __restrict__ s, int n) {
    int i = blockIdx.x * 256 + threadIdx.x;
    if (i >= n) return;
    float acc = 0.f;
    int beg = rowptr[i], end = rowptr[i + 1];
    int e = beg;
    for (; e + 3 < end; e += 4) {
        acc += (t[colarr[e]] + t[colarr[e + 1]]) + (t[colarr[e + 2]] + t[colarr[e + 3]]);
    }
    for (; e < end; ++e) acc += t[colarr[e]];
    s[i] = (acc + t[i]) * dinv[i] + b4[0];
}

// batch is sorted: record each graph's node range
__global__ void bounds_kernel(const int* __restrict__ batch, int* __restrict__ gstart,
                              int* __restrict__ gend, int n) {
    int i = blockIdx.x * 256 + threadIdx.x;
    if (i >= n) return;
    int g = batch[i];
    if (i == 0     || batch[i - 1] != g) gstart[g] = i;
    if (i == n - 1 || batch[i + 1] != g) gend[g]   = i + 1;
}

// one wave per graph: mean over its node range + sigmoid, straight to d_out
__global__ void pool2_kernel(const float* __restrict__ sv, const int* __restrict__ gstart,
                             const int* __restrict__ gend, float* __restrict__ out, int ng) {
    int g = blockIdx.x * 4 + (threadIdx.x >> 6);
    if (g >= ng) return;
    int lane = threadIdx.x & 63;
    int beg = gstart[g], end = gend[g];
    float acc = 0.f;
    for (int i = beg + lane; i < end; i += 64) acc += sv[i];
    #pragma unroll
    for (int off = 32; off; off >>= 1) acc += __shfl_xor(acc, off);
    if (lane == 0) {
        float c = fmaxf((float)(end - beg), 1.0f);
        float v = acc / c;
        out[g] = 1.0f / (1.0f + expf(-v));
    }
}

extern "C" void kernel_launch(void* const* d_in, const int* in_sizes, int n_in,
                              void* d_out, int out_size, void* d_ws, size_t ws_size,
                              hipStream_t stream) {
    const float* x    = (const float*)d_in[0];
    const int*   eidx = (const int*)d_in[1];
    const int*   batch= (const int*)d_in[2];
    const float* W1 = (const float*)d_in[3];
    const float* b1 = (const float*)d_in[4];
    const float* W2 = (const float*)d_in[5];
    const float* b2 = (const float*)d_in[6];
    const float* W3 = (const float*)d_in[7];
    const float* b3 = (const float*)d_in[8];
    const float* W4 = (const float*)d_in[9];
    const float* b4 = (const float*)d_in[10];

    const int n  = in_sizes[0] / 6;
    const int e  = in_sizes[1] / 2;
    const int ng = out_size;
    const int* src = eidx;
    const int* dst = eidx + e;
    const int nbuk = (n + BKT - 1) / BKT;   // 1563 @ n=100k (MAXBUK cap)

    // workspace layout
    char* ws = (char*)d_ws;
    float* bufA   = (float*)ws; ws += (size_t)n * 128 * 4;   // xs / CSR scratch / hb
    void*  gbuf   = (void*)ws;  ws += (size_t)n * 128 * 4;   // ax / fp8 gout
    int*   colarr = (int*)ws;   ws += (size_t)e * 4;
    int*   rowptr = (int*)ws;   ws += ((size_t)n + 4) * 4;
    float* dinv   = (float*)ws; ws += (size_t)n * 4;
    float* t      = (float*)ws; ws += (size_t)n * 4;
    float* sv     = (float*)ws; ws += (size_t)n * 4;
    int*   gstart = (int*)ws;   ws += 1024;
    int*   gend   = (int*)ws;   ws += 1024;
    unsigned short* wtg2 = (unsigned short*)ws; ws += 128 * WTP * 2;
    unsigned short* wtg3 = (unsigned short*)ws; ws += 128 * WTP * 2;

    // CSR-build scratch in bufA's tail (dead before gemm1 writes hb there)
    char* tail = (char*)bufA;
    int* part    = (int*)(tail + (16u << 20));   // e ints (6.4MB)
    int* hmatT   = (int*)(tail + (24u << 20));   // nbuk*NCH ints
    int* totals  = (int*)(tail + (26u << 20));   // nbuk ints
    int* bukBase = (int*)(tail + (27u << 20));   // nbuk+1 ints

    float* xs = bufA;                       // [n,6] prescaled x
    float* ax = (float*)gbuf;               // [n,6] aggregated
    unsigned short* hb = (unsigned short*)bufA;  // [n,128] bf16 h

    const int nb = (n + 255) / 256;
    const int nw = (n + 3) / 4;
    const int gb = (n + MB - 1) / MB;

    // ---- CSR build (no device-scope atomics) ----
    hist_bucket<<<NCH, 256, 0, stream>>>(dst, hmatT, e, nbuk);
    scan_chunks<<<(nbuk + 3) / 4, 256, 0, stream>>>(hmatT, totals, nbuk);
    scan_kernel<<<1, 1024, 0, stream>>>(totals, bukBase, nbuk);
    partition_kernel<<<NCH, 256, 0, stream>>>(src, dst, hmatT, bukBase, part, e, nbuk);
    bucket_csr<<<nbuk, 256, 0, stream>>>(part, bukBase, colarr, rowptr, dinv, n, e);

    // ---- weight prep (both layers, one launch) ----
    wconv_kernel<<<128, 256, 0, stream>>>(W2, wtg2, W3, wtg3);

    // ---- layer 1: prescale x, aggregate (6-dim), then GEMM -> bf16 h ----
    xscale_kernel<<<(n * 6 + 255) / 256, 256, 0, stream>>>(x, dinv, xs, n);
    aggx_kernel<<<nb, 256, 0, stream>>>(xs, rowptr, colarr, dinv, ax, n);
    gemm1_kernel<<<(n * 128 + 255) / 256, 256, 0, stream>>>(ax, W1, b1, hb, n);

    // ---- layer 2 ----
    gemm128_mfma<<<gb, 256, 0, stream>>>(hb, wtg2, dinv, (int*)gbuf, n);
    agg128_kernel<<<nw, 256, 0, stream>>>(gbuf, rowptr, colarr, dinv, b2, hb, n, 1);

    // ---- layer 3 ----
    gemm128_mfma<<<gb, 256, 0, stream>>>(hb, wtg3, dinv, (int*)gbuf, n);
    agg128_kernel<<<nw, 256, 0, stream>>>(gbuf, rowptr, colarr, dinv, b3, hb, n, 1);

    // ---- layer 4: project to scalar, aggregate ----
    head_kernel<<<nw, 256, 0, stream>>>(hb, W4, dinv, t, n);
    aggs_kernel<<<nb, 256, 0, stream>>>(t, rowptr, colarr, dinv, b4, sv, n);

    // ---- pool: sorted batch -> segment bounds + per-graph wave mean ----
    hipMemsetAsync(gstart, 0, 2048, stream);
    bounds_kernel<<<nb, 256, 0, stream>>>(batch, gstart, gend, n);
    pool2_kernel<<<(ng + 3) / 4, 256, 0, stream>>>(sv, gstart, gend, (float*)d_out, ng);
}